// Round 8
// baseline (19323.201 us; speedup 1.0000x reference)
//
#include <hip/hip_runtime.h>
#include <stdint.h>

#define B_   256
#define T_   160
#define DIN_ 40
#define H_   768
#define NG_  3072   // 4*H
#define KP0_ 1024   // 48 x-pad | 768 h | pad to 1024
#define KP12_ 1536  // 768 hin | 768 hown
#define XC_  48     // padded x columns

typedef _Float16 f16;
typedef _Float16 half8 __attribute__((ext_vector_type(8)));
typedef float f32x4 __attribute__((ext_vector_type(4)));

#define AS1C(p) ((const __attribute__((address_space(1))) uint32_t*)(p))
#define AS3(p)  ((__attribute__((address_space(3))) uint32_t*)(p))

struct Params {
  const f16* wt0; const f16* wt1; const f16* wt2;
  const float* bq; const f16* x16;
  f16* hs0; f16* hs1; f16* hs2;
  const f16* zpad; unsigned* cnt; unsigned* claim; unsigned* ibar; float* out;
};

__device__ __forceinline__ float sigmoid_f(float x) { return 1.f / (1.f + __expf(-x)); }
__device__ __forceinline__ float tanh_f(float x) {
  x = fminf(15.f, fmaxf(-15.f, x));
  float e = __expf(2.f * x);
  return (e - 1.f) / (e + 1.f);
}

// Weights -> fp16, transposed [n'][k], gate-interleaved cols n' = 4*j + g.
__global__ void conv_w(const float* __restrict__ Wi, const float* __restrict__ Wh,
                       int in_dim, int hoff, int Kp, f16* __restrict__ dst) {
  __shared__ f16 tile[64][66];
  const int k0 = blockIdx.x * 64;
  const int by = blockIdx.y;            // 0..47
  const int g = by / 12, j0 = (by % 12) * 64;
  const int tid = threadIdx.x;
  #pragma unroll
  for (int it = 0; it < 16; ++it) {
    int idx = it * 256 + tid;
    int jj = idx & 63;
    int kk = idx >> 6;
    int k = k0 + kk;
    int oc = g * H_ + j0 + jj;
    float v = 0.f;
    if (k < in_dim) v = Wi[(size_t)k * NG_ + oc];
    else if (k >= hoff && k < hoff + H_) v = Wh[(size_t)(k - hoff) * NG_ + oc];
    tile[kk][jj] = (f16)v;
  }
  __syncthreads();
  #pragma unroll
  for (int it = 0; it < 16; ++it) {
    int idx = it * 256 + tid;
    int kk = idx & 63;
    int jj = idx >> 6;
    int np = 4 * (j0 + jj) + g;
    dst[(size_t)np * Kp + k0 + kk] = tile[kk][jj];
  }
}

__global__ void conv_b(const float* __restrict__ b0, const float* __restrict__ b1,
                       const float* __restrict__ b2, float* __restrict__ bq) {
  int id = blockIdx.x * 256 + threadIdx.x;
  if (id < 3 * NG_) {
    int l = id / NG_, np = id % NG_;
    int j = np >> 2, g = np & 3;
    const float* s = (l == 0) ? b0 : (l == 1 ? b1 : b2);
    bq[id] = s[g * H_ + j];
  }
}

// x [B,T,40] fp32 -> x16 [T,B,48] fp16 (cols 40..47 zero)
__global__ void conv_x(const float* __restrict__ x, f16* __restrict__ x16) {
  int id = blockIdx.x * 256 + threadIdx.x;
  if (id >= T_ * B_ * XC_) return;
  int k = id % XC_;
  int b = (id / XC_) % B_;
  int t = id / (XC_ * B_);
  float v = (k < DIN_) ? x[(size_t)b * (T_ * DIN_) + t * DIN_ + k] : 0.f;
  x16[id] = (f16)v;
}

// L1-bypassing (sc0) load: reads the XCD-local L2, which is the visibility
// point for all intra-XCD communication in this kernel.
__device__ __forceinline__ unsigned ld_l2(const unsigned* p) {
  unsigned v;
  asm volatile("global_load_dword %0, %1, off sc0\n\ts_waitcnt vmcnt(0)"
               : "=v"(v) : "v"(p) : "memory");
  return v;
}

template<int L>
__device__ __forceinline__ void run_layer(
    const f16* __restrict__ WT, const f16* __restrict__ hin, f16* __restrict__ hown,
    const float* __restrict__ bql, const f16* __restrict__ zpad, float* __restrict__ out,
    unsigned* flg, unsigned& iter, f16* Abuf, float* zred, float* bqs,
    int tid, int lane, int w, int kw, int cw, int btile, int ntile, int n0) {
  constexpr int KP  = (L == 0) ? KP0_ : KP12_;
  constexpr int KQ  = KP / 4;                 // k per wave (4-way k-split)
  constexpr int NKT = KQ / 32;                // 32-k tiles per wave: L0=8, L12=12
  constexpr int CH  = (L == 0) ? 128 : 96;    // 16B chunks per A row in addressed block

  if (tid < 96) bqs[tid] = bql[tid];

  // ---- persistent B fragments: 3 col-tiles x NKT k-tiles, 4 VGPR each (144 max)
  half8 breg[3 * NKT];
  #pragma unroll
  for (int ct = 0; ct < 3; ++ct) {
    #pragma unroll
    for (int kt = 0; kt < NKT; ++kt) {
      int col = n0 + cw * 48 + ct * 16 + (lane & 15);
      int k = kw * KQ + kt * 32 + (lane >> 4) * 8;
      breg[ct * NKT + kt] = *(const half8*)(WT + (size_t)col * KP + k);
    }
  }

  // hin staging by waves 6,7 (no gate work): hin is the finished previous
  // layer's output (written by this same XCD's WGs) -> stable any time.
  auto stage_hin = [&](int slot) {
    #pragma unroll
    for (int i = 0; i < 24; ++i) {
      int cb = (w - 6) * 1536 + i * 64;
      int idx = cb + lane;
      int row = idx / 96;
      int c = idx - row * 96;
      int cg = c ^ (row & 7);
      int b = btile * 32 + row;
      const f16* src = hin + ((size_t)slot * B_ + b) * H_ + cg * 8;
      __builtin_amdgcn_global_load_lds(AS1C(src), AS3(Abuf + (size_t)cb * 8), 16, 0, 0);
    }
  };
  if (L > 0 && tid >= 384) stage_hin(1);   // h_{l-1}(0) for step 0

  // one gate item per thread (tid<384): item id = row*12+jp; 8 gate cols = 2 h cols
  const int id = tid;
  const int grow = id / 12, gjp = id - grow * 12;
  const int gb = btile * 32 + grow;
  const int ghc0 = ntile * 24 + 2 * gjp;
  float c0 = 0.f, c1 = 0.f, oa0 = 0.f, oa1 = 0.f;

  for (int t = 0; t < T_; ++t) {
    // ---- step-start staging
    if (L == 0) {
      // full A tile 32x1024 f16 = 4096 chunks over 8 waves
      #pragma unroll
      for (int i = 0; i < 8; ++i) {
        int cb = w * 512 + i * 64;
        int idx = cb + lane;
        int row = idx >> 7;
        int c = idx & 127;
        int cg = c ^ (row & 7);
        int b = btile * 32 + row;
        const f16* src;
        if (cg < 6)        src = hin + ((size_t)t * B_ + b) * XC_ + cg * 8;   // x16
        else if (cg < 102) src = hown + ((size_t)t * B_ + b) * H_ + (cg - 6) * 8;
        else               src = zpad;
        __builtin_amdgcn_global_load_lds(AS1C(src), AS3(Abuf + (size_t)cb * 8), 16, 0, 0);
      }
    } else if (w >= 4) {
      // hown(t-1) half: 3072 chunks over waves 4-7 = 12 iters
      #pragma unroll
      for (int i = 0; i < 12; ++i) {
        int cb = (w - 4) * 768 + i * 64;
        int idx = cb + lane;
        int row = idx / 96;
        int c = idx - row * 96;
        int cg = c ^ (row & 7);
        int b = btile * 32 + row;
        const f16* src = hown + ((size_t)t * B_ + b) * H_ + cg * 8;
        __builtin_amdgcn_global_load_lds(AS1C(src), AS3(Abuf + (size_t)(32 * 768 + cb * 8)), 16, 0, 0);
      }
    }
    asm volatile("s_waitcnt vmcnt(0)" ::: "memory");
    __syncthreads();

    // ---- MFMA: wave tile 32 rows x 48 cols over its k-quarter
    f32x4 acc[2][3] = {};
    const char* Ab = (const char*)(Abuf + (L == 0 ? 0 : (kw >> 1) * 32 * 768));
    const int cbase = (L == 0) ? kw * 32 : (kw & 1) * 48;
    #pragma unroll
    for (int kt = 0; kt < NKT; ++kt) {
      int c = cbase + kt * 4 + (lane >> 4);
      int row0 = (lane & 15);
      half8 a0 = *(const half8*)(Ab + (size_t)row0 * (CH * 16) + (size_t)(c ^ (row0 & 7)) * 16);
      int row1 = 16 + (lane & 15);
      half8 a1 = *(const half8*)(Ab + (size_t)row1 * (CH * 16) + (size_t)(c ^ (row1 & 7)) * 16);
      #pragma unroll
      for (int ct = 0; ct < 3; ++ct) {
        acc[0][ct] = __builtin_amdgcn_mfma_f32_16x16x32_f16(a0, breg[ct * NKT + kt], acc[0][ct], 0, 0, 0);
        acc[1][ct] = __builtin_amdgcn_mfma_f32_16x16x32_f16(a1, breg[ct * NKT + kt], acc[1][ct], 0, 0, 0);
      }
    }

    // ---- partial Z -> LDS, stride-96 layout: addr = kw*3072 + row*96 + col
    {
      float* zr = zred + kw * 3072;
      #pragma unroll
      for (int rt = 0; rt < 2; ++rt) {
        #pragma unroll
        for (int ct = 0; ct < 3; ++ct) {
          int row = rt * 16 + (lane >> 4) * 4;
          int col = cw * 48 + ct * 16 + (lane & 15);
          #pragma unroll
          for (int r4 = 0; r4 < 4; ++r4)
            zr[(size_t)(row + r4) * 96 + col] = acc[rt][ct][r4];
        }
      }
    }
    __syncthreads();

    // ---- waves 6,7: prefetch hin(t+1)'s slot (t+2) while others do gates
    if (tid >= 384) {
      if (L > 0 && t + 1 < T_) stage_hin(t + 2);
    } else {
      // gate item: reads are lane-linear (id*8 dwords)
      const float* z = zred + (size_t)id * 8;
      f32x4 za = *(const f32x4*)(z)        + *(const f32x4*)(z + 3072)
               + *(const f32x4*)(z + 6144) + *(const f32x4*)(z + 9216);
      f32x4 zb = *(const f32x4*)(z + 4)        + *(const f32x4*)(z + 3076)
               + *(const f32x4*)(z + 6148)     + *(const f32x4*)(z + 9220);
      za += *(const f32x4*)(bqs + gjp * 8);
      zb += *(const f32x4*)(bqs + gjp * 8 + 4);
      float i0 = sigmoid_f(za[0]), f0 = sigmoid_f(za[1]), g0 = tanh_f(za[2]), o0 = sigmoid_f(za[3]);
      float i1 = sigmoid_f(zb[0]), f1 = sigmoid_f(zb[1]), g1 = tanh_f(zb[2]), o1 = sigmoid_f(zb[3]);
      float cn0 = f0 * c0 + i0 * g0;
      float cn1 = f1 * c1 + i1 * g1;
      c0 = cn0; c1 = cn1;
      float h0 = o0 * tanh_f(cn0);
      float h1 = o1 * tanh_f(cn1);
      f16 hh0 = (f16)h0, hh1 = (f16)h1;
      unsigned u = ((unsigned)__builtin_bit_cast(uint16_t, hh1) << 16)
                 |  (unsigned)__builtin_bit_cast(uint16_t, hh0);
      // plain write-through store: lands in THIS XCD's L2; all consumers of
      // this h value are WGs on the same XCD (claim-grouped), so L2 is the
      // coherence point -- no agent-scope (L3) round trip needed.
      unsigned* hp = (unsigned*)(hown + ((size_t)(t + 1) * B_ + gb) * H_ + ghc0);
      __hip_atomic_store(hp, u, __ATOMIC_RELAXED, __HIP_MEMORY_SCOPE_WORKGROUP);
      if (L == 2) {
        oa0 += h0; oa1 += h1;
        if (t == T_ - 1) {
          out[(size_t)gb * H_ + ghc0]     = oa0 * (1.f / T_);
          out[(size_t)gb * H_ + ghc0 + 1] = oa1 * (1.f / T_);
        }
      }
    }

    // ---- drain h-stores to L2 (gate waves only; prefetch waves keep loads in flight)
    if (tid < 384) { asm volatile("s_waitcnt vmcnt(0)" ::: "memory"); }
    __syncthreads();
    ++iter;
    // ---- XCD-local distributed barrier: plain flag store (lands in local L2),
    // wave 5 gather-polls all 32 flags with sc0 (L1-bypass, L2-read) loads.
    // Bounded-spin fallback to agent-scope loads guards against sc0 mis-semantics.
    if (w == 5) {
      if (lane == 0)
        __hip_atomic_store(flg + (size_t)ntile * 32, iter,
                           __ATOMIC_RELAXED, __HIP_MEMORY_SCOPE_WORKGROUP);
      unsigned* fp = flg + (size_t)(lane & 31) * 32;
      int spins = 0;
      for (;;) {
        unsigned v = (spins < 256)
            ? ld_l2(fp)
            : __hip_atomic_load(fp, __ATOMIC_RELAXED, __HIP_MEMORY_SCOPE_AGENT);
        if (__ballot(v >= iter) == ~0ull) break;
        ++spins;
        __builtin_amdgcn_s_sleep(1);
      }
    }
    __syncthreads();
  }
}

__global__ __launch_bounds__(512, 2) void lstm_main(Params p) {
  __shared__ __align__(16) f16 Abuf[2 * 32 * 768];        // 96 KB
  __shared__ __align__(16) float zred[4 * 32 * 96];       // 48 KB (4 k-partials)
  __shared__ __align__(16) float bqs[96];
  __shared__ unsigned claim_s[2];

  const int tid = threadIdx.x;
  const int lane = tid & 63;
  const int w = tid >> 6;                  // 0..7
  const int kw = w >> 1, cw = w & 1;       // k-quarter 0..3, col-half 0..1

  // ---- dynamic XCD-local grouping: group = PHYSICAL XCD (detected, not
  // assumed), ntile = claim order within the XCD. 148 KB LDS => exactly
  // 1 WG/CU => exactly 32 WGs per XCD => slots 0..31 fill exactly.
  if (tid == 0) {
    unsigned xcc;
    asm volatile("s_getreg_b32 %0, hwreg(HW_REG_XCC_ID)" : "=s"(xcc));
    xcc &= 7u;
    unsigned slot = __hip_atomic_fetch_add(p.claim + xcc, 1u,
                                           __ATOMIC_RELAXED, __HIP_MEMORY_SCOPE_AGENT);
    claim_s[0] = xcc;
    claim_s[1] = slot & 31u;
  }
  __syncthreads();
  const int btile = (int)claim_s[0];       // batch tile == XCD id
  const int ntile = (int)claim_s[1];       // 0..31 (96 gate cols)
  unsigned* flg = p.cnt + (size_t)btile * 1024;   // 32 flags x 128B stride
  const int n0 = ntile * 96;
  unsigned iter = 0;

  // ---- init: zero OUR flag in the local L2 (kills cross-replay staleness),
  // then a one-time agent-scope group barrier so no one polls unzeroed flags.
  if (tid == 0) {
    __hip_atomic_store(flg + (size_t)ntile * 32, 0u,
                       __ATOMIC_RELAXED, __HIP_MEMORY_SCOPE_WORKGROUP);
    asm volatile("s_waitcnt vmcnt(0)" ::: "memory");
    __hip_atomic_fetch_add(p.ibar + btile, 1u, __ATOMIC_RELEASE, __HIP_MEMORY_SCOPE_AGENT);
    while (__hip_atomic_load(p.ibar + btile, __ATOMIC_RELAXED, __HIP_MEMORY_SCOPE_AGENT) < 32u)
      __builtin_amdgcn_s_sleep(2);
  }
  __syncthreads();

  run_layer<0>(p.wt0, p.x16, p.hs0, p.bq + 0 * NG_ + n0, p.zpad, p.out, flg, iter,
               Abuf, zred, bqs, tid, lane, w, kw, cw, btile, ntile, n0);
  run_layer<1>(p.wt1, p.hs0, p.hs1, p.bq + 1 * NG_ + n0, p.zpad, p.out, flg, iter,
               Abuf, zred, bqs, tid, lane, w, kw, cw, btile, ntile, n0);
  run_layer<2>(p.wt2, p.hs1, p.hs2, p.bq + 2 * NG_ + n0, p.zpad, p.out, flg, iter,
               Abuf, zred, bqs, tid, lane, w, kw, cw, btile, ntile, n0);
}

extern "C" void kernel_launch(void* const* d_in, const int* in_sizes, int n_in,
                              void* d_out, int out_size, void* d_ws, size_t ws_size,
                              hipStream_t stream) {
  const float* x   = (const float*)d_in[0];
  const float* Wi0 = (const float*)d_in[1];
  const float* Wh0 = (const float*)d_in[2];
  const float* b0  = (const float*)d_in[3];
  const float* Wi1 = (const float*)d_in[4];
  const float* Wh1 = (const float*)d_in[5];
  const float* b1  = (const float*)d_in[6];
  const float* Wi2 = (const float*)d_in[7];
  const float* Wh2 = (const float*)d_in[8];
  const float* b2  = (const float*)d_in[9];

  char* wsb = (char*)d_ws;
  size_t off = 0;
  auto nxt = [&](size_t sz) { char* p = wsb + off; off += (sz + 255) & ~(size_t)255; return p; };
  f16*      wt0  = (f16*)nxt((size_t)NG_ * KP0_ * 2);         // 6.3 MB
  f16*      wt1  = (f16*)nxt((size_t)NG_ * KP12_ * 2);        // 9.4 MB
  f16*      wt2  = (f16*)nxt((size_t)NG_ * KP12_ * 2);        // 9.4 MB
  float*    bq   = (float*)nxt((size_t)3 * NG_ * 4);
  f16*      x16  = (f16*)nxt((size_t)T_ * B_ * XC_ * 2);      // 3.9 MB
  f16*      hs0  = (f16*)nxt((size_t)(T_ + 1) * B_ * H_ * 2); // 60.4 MB
  f16*      hs1  = (f16*)nxt((size_t)(T_ + 1) * B_ * H_ * 2);
  f16*      hs2  = (f16*)nxt((size_t)(T_ + 1) * B_ * H_ * 2);
  f16*      zpad = (f16*)nxt(256);
  unsigned* cnt  = (unsigned*)nxt(8 * 1024 * 4);              // 8 groups x 32 flags x 128B
  unsigned* claim= (unsigned*)nxt(256);                       // 8 claim counters
  unsigned* ibar = (unsigned*)nxt(256);                       // 8 init-barrier counters
  if (off > ws_size) return;  // insufficient workspace

  const size_t slot_bytes = (size_t)B_ * H_ * 2;
  hipMemsetAsync(hs0, 0, slot_bytes, stream);
  hipMemsetAsync(hs1, 0, slot_bytes, stream);
  hipMemsetAsync(hs2, 0, slot_bytes, stream);
  hipMemsetAsync((void*)zpad, 0, 256, stream);
  hipMemsetAsync(cnt, 0, 8 * 1024 * 4, stream);
  hipMemsetAsync(claim, 0, 256, stream);
  hipMemsetAsync(ibar, 0, 256, stream);

  hipLaunchKernelGGL(conv_w, dim3(KP0_ / 64, 48), dim3(256), 0, stream, Wi0, Wh0, DIN_, XC_, KP0_, wt0);
  hipLaunchKernelGGL(conv_w, dim3(KP12_ / 64, 48), dim3(256), 0, stream, Wi1, Wh1, H_, H_, KP12_, wt1);
  hipLaunchKernelGGL(conv_w, dim3(KP12_ / 64, 48), dim3(256), 0, stream, Wi2, Wh2, H_, H_, KP12_, wt2);
  hipLaunchKernelGGL(conv_b, dim3((3 * NG_ + 255) / 256), dim3(256), 0, stream, b0, b1, b2, bq);
  hipLaunchKernelGGL(conv_x, dim3((T_ * B_ * XC_ + 255) / 256), dim3(256), 0, stream, x, x16);

  Params prm{wt0, wt1, wt2, bq, x16, hs0, hs1, hs2, zpad, cnt, claim, ibar, (float*)d_out};
  hipLaunchKernelGGL(lstm_main, dim3(256), dim3(512), 0, stream, prm);
}

// Round 9
// 5973.358 us; speedup vs baseline: 3.2349x; 3.2349x over previous
//
#include <hip/hip_runtime.h>
#include <stdint.h>

#define B_   256
#define T_   160
#define DIN_ 40
#define H_   768
#define NG_  3072   // 4*H
#define KP0_ 1024   // 48 x-pad | 768 h | pad to 1024
#define KP12_ 1536  // 768 hin | 768 hown
#define XC_  48     // padded x columns

typedef _Float16 f16;
typedef _Float16 half8 __attribute__((ext_vector_type(8)));
typedef float f32x4 __attribute__((ext_vector_type(4)));

#define AS1C(p) ((const __attribute__((address_space(1))) uint32_t*)(p))
#define AS3(p)  ((__attribute__((address_space(3))) uint32_t*)(p))

struct Params {
  const f16* wt0; const f16* wt1; const f16* wt2;
  const float* bq; const f16* x16;
  f16* hs0; f16* hs1; f16* hs2;
  const f16* zpad; unsigned* cnt; unsigned* claim; float* out;
};

__device__ __forceinline__ float sigmoid_f(float x) { return 1.f / (1.f + __expf(-x)); }
__device__ __forceinline__ float tanh_f(float x) {
  x = fminf(15.f, fmaxf(-15.f, x));
  float e = __expf(2.f * x);
  return (e - 1.f) / (e + 1.f);
}

// Weights -> fp16, transposed [n'][k], gate-interleaved cols n' = 4*j + g.
__global__ void conv_w(const float* __restrict__ Wi, const float* __restrict__ Wh,
                       int in_dim, int hoff, int Kp, f16* __restrict__ dst) {
  __shared__ f16 tile[64][66];
  const int k0 = blockIdx.x * 64;
  const int by = blockIdx.y;            // 0..47
  const int g = by / 12, j0 = (by % 12) * 64;
  const int tid = threadIdx.x;
  #pragma unroll
  for (int it = 0; it < 16; ++it) {
    int idx = it * 256 + tid;
    int jj = idx & 63;
    int kk = idx >> 6;
    int k = k0 + kk;
    int oc = g * H_ + j0 + jj;
    float v = 0.f;
    if (k < in_dim) v = Wi[(size_t)k * NG_ + oc];
    else if (k >= hoff && k < hoff + H_) v = Wh[(size_t)(k - hoff) * NG_ + oc];
    tile[kk][jj] = (f16)v;
  }
  __syncthreads();
  #pragma unroll
  for (int it = 0; it < 16; ++it) {
    int idx = it * 256 + tid;
    int kk = idx & 63;
    int jj = idx >> 6;
    int np = 4 * (j0 + jj) + g;
    dst[(size_t)np * Kp + k0 + kk] = tile[kk][jj];
  }
}

__global__ void conv_b(const float* __restrict__ b0, const float* __restrict__ b1,
                       const float* __restrict__ b2, float* __restrict__ bq) {
  int id = blockIdx.x * 256 + threadIdx.x;
  if (id < 3 * NG_) {
    int l = id / NG_, np = id % NG_;
    int j = np >> 2, g = np & 3;
    const float* s = (l == 0) ? b0 : (l == 1 ? b1 : b2);
    bq[id] = s[g * H_ + j];
  }
}

// x [B,T,40] fp32 -> x16 [T,B,48] fp16 (cols 40..47 zero)
__global__ void conv_x(const float* __restrict__ x, f16* __restrict__ x16) {
  int id = blockIdx.x * 256 + threadIdx.x;
  if (id >= T_ * B_ * XC_) return;
  int k = id % XC_;
  int b = (id / XC_) % B_;
  int t = id / (XC_ * B_);
  float v = (k < DIN_) ? x[(size_t)b * (T_ * DIN_) + t * DIN_ + k] : 0.f;
  x16[id] = (f16)v;
}

template<int L>
__device__ __forceinline__ void run_layer(
    const f16* __restrict__ WT, const f16* __restrict__ hin, f16* __restrict__ hown,
    const float* __restrict__ bql, const f16* __restrict__ zpad, float* __restrict__ out,
    unsigned* flg, unsigned& iter, f16* Abuf, float* zred, float* bqs,
    int tid, int lane, int w, int kw, int cw, int btile, int ntile, int n0) {
  constexpr int KP  = (L == 0) ? KP0_ : KP12_;
  constexpr int KQ  = KP / 4;                 // k per wave (4-way k-split)
  constexpr int NKT = KQ / 32;                // 32-k tiles per wave: L0=8, L12=12
  constexpr int CH  = (L == 0) ? 128 : 96;    // 16B chunks per A row in addressed block

  if (tid < 96) bqs[tid] = bql[tid];

  // ---- persistent B fragments: 3 col-tiles x NKT k-tiles, 4 VGPR each (144 max)
  half8 breg[3 * NKT];
  #pragma unroll
  for (int ct = 0; ct < 3; ++ct) {
    #pragma unroll
    for (int kt = 0; kt < NKT; ++kt) {
      int col = n0 + cw * 48 + ct * 16 + (lane & 15);
      int k = kw * KQ + kt * 32 + (lane >> 4) * 8;
      breg[ct * NKT + kt] = *(const half8*)(WT + (size_t)col * KP + k);
    }
  }

  // hin staging by waves 6,7 (no gate work): hin is the finished previous
  // layer's output (written by this same XCD's WGs) -> stable any time.
  auto stage_hin = [&](int slot) {
    #pragma unroll
    for (int i = 0; i < 24; ++i) {
      int cb = (w - 6) * 1536 + i * 64;
      int idx = cb + lane;
      int row = idx / 96;
      int c = idx - row * 96;
      int cg = c ^ (row & 7);
      int b = btile * 32 + row;
      const f16* src = hin + ((size_t)slot * B_ + b) * H_ + cg * 8;
      __builtin_amdgcn_global_load_lds(AS1C(src), AS3(Abuf + (size_t)cb * 8), 16, 0, 0);
    }
  };
  if (L > 0 && tid >= 384) stage_hin(1);   // h_{l-1}(0) for step 0

  // one gate item per thread (tid<384): item id = row*12+jp; 8 gate cols = 2 h cols
  const int id = tid;
  const int grow = id / 12, gjp = id - grow * 12;
  const int gb = btile * 32 + grow;
  const int ghc0 = ntile * 24 + 2 * gjp;
  float c0 = 0.f, c1 = 0.f, oa0 = 0.f, oa1 = 0.f;

  for (int t = 0; t < T_; ++t) {
    // ---- step-start staging
    if (L == 0) {
      // full A tile 32x1024 f16 = 4096 chunks over 8 waves
      #pragma unroll
      for (int i = 0; i < 8; ++i) {
        int cb = w * 512 + i * 64;
        int idx = cb + lane;
        int row = idx >> 7;
        int c = idx & 127;
        int cg = c ^ (row & 7);
        int b = btile * 32 + row;
        const f16* src;
        if (cg < 6)        src = hin + ((size_t)t * B_ + b) * XC_ + cg * 8;   // x16
        else if (cg < 102) src = hown + ((size_t)t * B_ + b) * H_ + (cg - 6) * 8;
        else               src = zpad;
        __builtin_amdgcn_global_load_lds(AS1C(src), AS3(Abuf + (size_t)cb * 8), 16, 0, 0);
      }
    } else if (w >= 4) {
      // hown(t-1) half: 3072 chunks over waves 4-7 = 12 iters
      #pragma unroll
      for (int i = 0; i < 12; ++i) {
        int cb = (w - 4) * 768 + i * 64;
        int idx = cb + lane;
        int row = idx / 96;
        int c = idx - row * 96;
        int cg = c ^ (row & 7);
        int b = btile * 32 + row;
        const f16* src = hown + ((size_t)t * B_ + b) * H_ + cg * 8;
        __builtin_amdgcn_global_load_lds(AS1C(src), AS3(Abuf + (size_t)(32 * 768 + cb * 8)), 16, 0, 0);
      }
    }
    asm volatile("s_waitcnt vmcnt(0)" ::: "memory");
    __syncthreads();

    // ---- MFMA: wave tile 32 rows x 48 cols over its k-quarter
    f32x4 acc[2][3] = {};
    const char* Ab = (const char*)(Abuf + (L == 0 ? 0 : (kw >> 1) * 32 * 768));
    const int cbase = (L == 0) ? kw * 32 : (kw & 1) * 48;
    #pragma unroll
    for (int kt = 0; kt < NKT; ++kt) {
      int c = cbase + kt * 4 + (lane >> 4);
      int row0 = (lane & 15);
      half8 a0 = *(const half8*)(Ab + (size_t)row0 * (CH * 16) + (size_t)(c ^ (row0 & 7)) * 16);
      int row1 = 16 + (lane & 15);
      half8 a1 = *(const half8*)(Ab + (size_t)row1 * (CH * 16) + (size_t)(c ^ (row1 & 7)) * 16);
      #pragma unroll
      for (int ct = 0; ct < 3; ++ct) {
        acc[0][ct] = __builtin_amdgcn_mfma_f32_16x16x32_f16(a0, breg[ct * NKT + kt], acc[0][ct], 0, 0, 0);
        acc[1][ct] = __builtin_amdgcn_mfma_f32_16x16x32_f16(a1, breg[ct * NKT + kt], acc[1][ct], 0, 0, 0);
      }
    }

    // ---- partial Z -> LDS, stride-96 layout: addr = kw*3072 + row*96 + col
    {
      float* zr = zred + kw * 3072;
      #pragma unroll
      for (int rt = 0; rt < 2; ++rt) {
        #pragma unroll
        for (int ct = 0; ct < 3; ++ct) {
          int row = rt * 16 + (lane >> 4) * 4;
          int col = cw * 48 + ct * 16 + (lane & 15);
          #pragma unroll
          for (int r4 = 0; r4 < 4; ++r4)
            zr[(size_t)(row + r4) * 96 + col] = acc[rt][ct][r4];
        }
      }
    }
    __syncthreads();

    // ---- waves 6,7: prefetch hin(t+1)'s slot (t+2) while others do gates
    if (tid >= 384) {
      if (L > 0 && t + 1 < T_) stage_hin(t + 2);
    } else {
      // gate item: reads are lane-linear (id*8 dwords)
      const float* z = zred + (size_t)id * 8;
      f32x4 za = *(const f32x4*)(z)        + *(const f32x4*)(z + 3072)
               + *(const f32x4*)(z + 6144) + *(const f32x4*)(z + 9216);
      f32x4 zb = *(const f32x4*)(z + 4)        + *(const f32x4*)(z + 3076)
               + *(const f32x4*)(z + 6148)     + *(const f32x4*)(z + 9220);
      za += *(const f32x4*)(bqs + gjp * 8);
      zb += *(const f32x4*)(bqs + gjp * 8 + 4);
      float i0 = sigmoid_f(za[0]), f0 = sigmoid_f(za[1]), g0 = tanh_f(za[2]), o0 = sigmoid_f(za[3]);
      float i1 = sigmoid_f(zb[0]), f1 = sigmoid_f(zb[1]), g1 = tanh_f(zb[2]), o1 = sigmoid_f(zb[3]);
      float cn0 = f0 * c0 + i0 * g0;
      float cn1 = f1 * c1 + i1 * g1;
      c0 = cn0; c1 = cn1;
      float h0 = o0 * tanh_f(cn0);
      float h1 = o1 * tanh_f(cn1);
      f16 hh0 = (f16)h0, hh1 = (f16)h1;
      unsigned u = ((unsigned)__builtin_bit_cast(uint16_t, hh1) << 16)
                 |  (unsigned)__builtin_bit_cast(uint16_t, hh0);
      // plain write-through store: lands in THIS XCD's L2; all consumers of
      // this h value are WGs on the same XCD (claim-grouped), so L2 is the
      // coherence point -- no agent-scope (L3) round trip needed.
      unsigned* hp = (unsigned*)(hown + ((size_t)(t + 1) * B_ + gb) * H_ + ghc0);
      __hip_atomic_store(hp, u, __ATOMIC_RELAXED, __HIP_MEMORY_SCOPE_WORKGROUP);
      if (L == 2) {
        oa0 += h0; oa1 += h1;
        if (t == T_ - 1) {
          out[(size_t)gb * H_ + ghc0]     = oa0 * (1.f / T_);
          out[(size_t)gb * H_ + ghc0 + 1] = oa1 * (1.f / T_);
        }
      }
    }

    // ---- drain h-stores to L2 (gate waves only; prefetch waves keep loads in flight)
    if (tid < 384) { asm volatile("s_waitcnt vmcnt(0)" ::: "memory"); }
    __syncthreads();
    ++iter;
    // ---- distributed barrier, r6-proven scopes: flag store AGENT (to L3),
    // wave 5 gather-polls all 32 flags AGENT (L1/L2-bypass; sc0-only loads
    // were shown in r8 to be L1-served -> never observe remote stores).
    if (w == 5) {
      if (lane == 0)
        __hip_atomic_store(flg + (size_t)ntile * 32, iter,
                           __ATOMIC_RELAXED, __HIP_MEMORY_SCOPE_AGENT);
      unsigned* fp = flg + (size_t)(lane & 31) * 32;
      for (;;) {
        unsigned v = __hip_atomic_load(fp, __ATOMIC_RELAXED, __HIP_MEMORY_SCOPE_AGENT);
        if (__ballot(v >= iter) == ~0ull) break;
        __builtin_amdgcn_s_sleep(1);
      }
    }
    __syncthreads();
  }
}

__global__ __launch_bounds__(512, 2) void lstm_main(Params p) {
  __shared__ __align__(16) f16 Abuf[2 * 32 * 768];        // 96 KB
  __shared__ __align__(16) float zred[4 * 32 * 96];       // 48 KB (4 k-partials)
  __shared__ __align__(16) float bqs[96];
  __shared__ unsigned claim_s[2];

  const int tid = threadIdx.x;
  const int lane = tid & 63;
  const int w = tid >> 6;                  // 0..7
  const int kw = w >> 1, cw = w & 1;       // k-quarter 0..3, col-half 0..1

  // ---- dynamic XCD-local grouping: group = PHYSICAL XCD (detected, not
  // assumed), ntile = claim order within the XCD. 148 KB LDS => exactly
  // 1 WG/CU => exactly 32 WGs per XCD => slots 0..31 fill exactly.
  // (Validated in r8: correct output, FETCH_SIZE fell 4x.)
  if (tid == 0) {
    unsigned xcc;
    asm volatile("s_getreg_b32 %0, hwreg(HW_REG_XCC_ID)" : "=s"(xcc));
    xcc &= 7u;
    unsigned slot = __hip_atomic_fetch_add(p.claim + xcc, 1u,
                                           __ATOMIC_RELAXED, __HIP_MEMORY_SCOPE_AGENT);
    claim_s[0] = xcc;
    claim_s[1] = slot & 31u;
  }
  __syncthreads();
  const int btile = (int)claim_s[0];       // batch tile == XCD id
  const int ntile = (int)claim_s[1];       // 0..31 (96 gate cols)
  unsigned* flg = p.cnt + (size_t)btile * 1024;   // 32 flags x 128B stride
  const int n0 = ntile * 96;
  unsigned iter = 0;

  run_layer<0>(p.wt0, p.x16, p.hs0, p.bq + 0 * NG_ + n0, p.zpad, p.out, flg, iter,
               Abuf, zred, bqs, tid, lane, w, kw, cw, btile, ntile, n0);
  run_layer<1>(p.wt1, p.hs0, p.hs1, p.bq + 1 * NG_ + n0, p.zpad, p.out, flg, iter,
               Abuf, zred, bqs, tid, lane, w, kw, cw, btile, ntile, n0);
  run_layer<2>(p.wt2, p.hs1, p.hs2, p.bq + 2 * NG_ + n0, p.zpad, p.out, flg, iter,
               Abuf, zred, bqs, tid, lane, w, kw, cw, btile, ntile, n0);
}

extern "C" void kernel_launch(void* const* d_in, const int* in_sizes, int n_in,
                              void* d_out, int out_size, void* d_ws, size_t ws_size,
                              hipStream_t stream) {
  const float* x   = (const float*)d_in[0];
  const float* Wi0 = (const float*)d_in[1];
  const float* Wh0 = (const float*)d_in[2];
  const float* b0  = (const float*)d_in[3];
  const float* Wi1 = (const float*)d_in[4];
  const float* Wh1 = (const float*)d_in[5];
  const float* b1  = (const float*)d_in[6];
  const float* Wi2 = (const float*)d_in[7];
  const float* Wh2 = (const float*)d_in[8];
  const float* b2  = (const float*)d_in[9];

  char* wsb = (char*)d_ws;
  size_t off = 0;
  auto nxt = [&](size_t sz) { char* p = wsb + off; off += (sz + 255) & ~(size_t)255; return p; };
  f16*      wt0  = (f16*)nxt((size_t)NG_ * KP0_ * 2);         // 6.3 MB
  f16*      wt1  = (f16*)nxt((size_t)NG_ * KP12_ * 2);        // 9.4 MB
  f16*      wt2  = (f16*)nxt((size_t)NG_ * KP12_ * 2);        // 9.4 MB
  float*    bq   = (float*)nxt((size_t)3 * NG_ * 4);
  f16*      x16  = (f16*)nxt((size_t)T_ * B_ * XC_ * 2);      // 3.9 MB
  f16*      hs0  = (f16*)nxt((size_t)(T_ + 1) * B_ * H_ * 2); // 60.4 MB
  f16*      hs1  = (f16*)nxt((size_t)(T_ + 1) * B_ * H_ * 2);
  f16*      hs2  = (f16*)nxt((size_t)(T_ + 1) * B_ * H_ * 2);
  f16*      zpad = (f16*)nxt(256);
  unsigned* cnt  = (unsigned*)nxt(8 * 1024 * 4);              // 8 groups x 32 flags x 128B
  unsigned* claim= (unsigned*)nxt(256);                       // 8 claim counters
  if (off > ws_size) return;  // insufficient workspace

  const size_t slot_bytes = (size_t)B_ * H_ * 2;
  hipMemsetAsync(hs0, 0, slot_bytes, stream);
  hipMemsetAsync(hs1, 0, slot_bytes, stream);
  hipMemsetAsync(hs2, 0, slot_bytes, stream);
  hipMemsetAsync((void*)zpad, 0, 256, stream);
  hipMemsetAsync(cnt, 0, 8 * 1024 * 4, stream);
  hipMemsetAsync(claim, 0, 256, stream);

  hipLaunchKernelGGL(conv_w, dim3(KP0_ / 64, 48), dim3(256), 0, stream, Wi0, Wh0, DIN_, XC_, KP0_, wt0);
  hipLaunchKernelGGL(conv_w, dim3(KP12_ / 64, 48), dim3(256), 0, stream, Wi1, Wh1, H_, H_, KP12_, wt1);
  hipLaunchKernelGGL(conv_w, dim3(KP12_ / 64, 48), dim3(256), 0, stream, Wi2, Wh2, H_, H_, KP12_, wt2);
  hipLaunchKernelGGL(conv_b, dim3((3 * NG_ + 255) / 256), dim3(256), 0, stream, b0, b1, b2, bq);
  hipLaunchKernelGGL(conv_x, dim3((T_ * B_ * XC_ + 255) / 256), dim3(256), 0, stream, x, x16);

  Params prm{wt0, wt1, wt2, bq, x16, hs0, hs1, hs2, zpad, cnt, claim, (float*)d_out};
  hipLaunchKernelGGL(lstm_main, dim3(256), dim3(512), 0, stream, prm);
}

// Round 10
// 5569.324 us; speedup vs baseline: 3.4696x; 1.0725x over previous
//
#include <hip/hip_runtime.h>
#include <stdint.h>

#define B_   256
#define T_   160
#define DIN_ 40
#define H_   768
#define NG_  3072   // 4*H
#define KP0_ 1024   // 48 x-pad | 768 h | pad to 1024
#define KP12_ 1536  // 768 hin | 768 hown
#define XC_  48     // padded x columns
#define RS_  16     // h ring slots (per-XCD L2-resident recurrence window)
#define FR_  64     // barrier fast-flag rotation
#define BH_  ((size_t)B_ * H_)

typedef _Float16 f16;
typedef _Float16 half8 __attribute__((ext_vector_type(8)));
typedef float f32x4 __attribute__((ext_vector_type(4)));

#define AS1C(p) ((const __attribute__((address_space(1))) uint32_t*)(p))
#define AS3(p)  ((__attribute__((address_space(3))) uint32_t*)(p))

struct Params {
  const f16* wt0; const f16* wt1; const f16* wt2;
  const float* bq; const f16* x16;
  f16* hs0; f16* hs1;            // time-indexed arrays (inter-layer hin); L2 has none
  f16* ring;                     // [3][RS_][B][H] intra-layer recurrence ring
  const f16* zpad; unsigned* cnt; unsigned* flgW; unsigned* claim; float* out;
};

__device__ __forceinline__ float sigmoid_f(float x) { return 1.f / (1.f + __expf(-x)); }
__device__ __forceinline__ float tanh_f(float x) {
  x = fminf(15.f, fmaxf(-15.f, x));
  float e = __expf(2.f * x);
  return (e - 1.f) / (e + 1.f);
}

// Weights -> fp16, transposed [n'][k], gate-interleaved cols n' = 4*j + g.
__global__ void conv_w(const float* __restrict__ Wi, const float* __restrict__ Wh,
                       int in_dim, int hoff, int Kp, f16* __restrict__ dst) {
  __shared__ f16 tile[64][66];
  const int k0 = blockIdx.x * 64;
  const int by = blockIdx.y;            // 0..47
  const int g = by / 12, j0 = (by % 12) * 64;
  const int tid = threadIdx.x;
  #pragma unroll
  for (int it = 0; it < 16; ++it) {
    int idx = it * 256 + tid;
    int jj = idx & 63;
    int kk = idx >> 6;
    int k = k0 + kk;
    int oc = g * H_ + j0 + jj;
    float v = 0.f;
    if (k < in_dim) v = Wi[(size_t)k * NG_ + oc];
    else if (k >= hoff && k < hoff + H_) v = Wh[(size_t)(k - hoff) * NG_ + oc];
    tile[kk][jj] = (f16)v;
  }
  __syncthreads();
  #pragma unroll
  for (int it = 0; it < 16; ++it) {
    int idx = it * 256 + tid;
    int kk = idx & 63;
    int jj = idx >> 6;
    int np = 4 * (j0 + jj) + g;
    dst[(size_t)np * Kp + k0 + kk] = tile[kk][jj];
  }
}

__global__ void conv_b(const float* __restrict__ b0, const float* __restrict__ b1,
                       const float* __restrict__ b2, float* __restrict__ bq) {
  int id = blockIdx.x * 256 + threadIdx.x;
  if (id < 3 * NG_) {
    int l = id / NG_, np = id % NG_;
    int j = np >> 2, g = np & 3;
    const float* s = (l == 0) ? b0 : (l == 1 ? b1 : b2);
    bq[id] = s[g * H_ + j];
  }
}

// x [B,T,40] fp32 -> x16 [T,B,48] fp16 (cols 40..47 zero)
__global__ void conv_x(const float* __restrict__ x, f16* __restrict__ x16) {
  int id = blockIdx.x * 256 + threadIdx.x;
  if (id >= T_ * B_ * XC_) return;
  int k = id % XC_;
  int b = (id / XC_) % B_;
  int t = id / (XC_ * B_);
  float v = (k < DIN_) ? x[(size_t)b * (T_ * DIN_) + t * DIN_ + k] : 0.f;
  x16[id] = (f16)v;
}

template<int L>
__device__ __forceinline__ void run_layer(
    const f16* __restrict__ WT, const f16* __restrict__ hin, f16* __restrict__ hown,
    f16* __restrict__ hring,
    const float* __restrict__ bql, const f16* __restrict__ zpad, float* __restrict__ out,
    unsigned* flg, unsigned* flgW, unsigned& iter, f16* Abuf, float* zred, float* bqs,
    int tid, int lane, int w, int kw, int cw, int btile, int ntile, int n0) {
  constexpr int KP  = (L == 0) ? KP0_ : KP12_;
  constexpr int KQ  = KP / 4;                 // k per wave (4-way k-split)
  constexpr int NKT = KQ / 32;                // 32-k tiles per wave: L0=8, L12=12
  constexpr int CH  = (L == 0) ? 128 : 96;    // 16B chunks per A row in addressed block

  if (tid < 96) bqs[tid] = bql[tid];

  // ---- persistent B fragments: 3 col-tiles x NKT k-tiles, 4 VGPR each (144 max)
  half8 breg[3 * NKT];
  #pragma unroll
  for (int ct = 0; ct < 3; ++ct) {
    #pragma unroll
    for (int kt = 0; kt < NKT; ++kt) {
      int col = n0 + cw * 48 + ct * 16 + (lane & 15);
      int k = kw * KQ + kt * 32 + (lane >> 4) * 8;
      breg[ct * NKT + kt] = *(const half8*)(WT + (size_t)col * KP + k);
    }
  }

  // hin staging by waves 6,7 (no gate work): hin is the finished previous
  // layer's time-indexed output (same-XCD producers) -> stable any time.
  auto stage_hin = [&](int slot) {
    #pragma unroll
    for (int i = 0; i < 24; ++i) {
      int cb = (w - 6) * 1536 + i * 64;
      int idx = cb + lane;
      int row = idx / 96;
      int c = idx - row * 96;
      int cg = c ^ (row & 7);
      int b = btile * 32 + row;
      const f16* src = hin + ((size_t)slot * B_ + b) * H_ + cg * 8;
      __builtin_amdgcn_global_load_lds(AS1C(src), AS3(Abuf + (size_t)cb * 8), 16, 0, 0);
    }
  };
  if (L > 0 && tid >= 384) stage_hin(1);   // h_{l-1}(0) for step 0

  // one gate item per thread (tid<384): item id = row*12+jp; 8 gate cols = 2 h cols
  const int id = tid;
  const int grow = id / 12, gjp = id - grow * 12;
  const int gb = btile * 32 + grow;
  const int ghc0 = ntile * 24 + 2 * gjp;
  float c0 = 0.f, c1 = 0.f, oa0 = 0.f, oa1 = 0.f;

  for (int t = 0; t < T_; ++t) {
    const int rslot = t & (RS_ - 1);
    // ---- step-start staging (hown/recurrence reads come from the L2-hot ring)
    if (L == 0) {
      // full A tile 32x1024 f16 = 4096 chunks over 8 waves
      #pragma unroll
      for (int i = 0; i < 8; ++i) {
        int cb = w * 512 + i * 64;
        int idx = cb + lane;
        int row = idx >> 7;
        int c = idx & 127;
        int cg = c ^ (row & 7);
        int b = btile * 32 + row;
        const f16* src;
        if (cg < 6)        src = hin + ((size_t)t * B_ + b) * XC_ + cg * 8;   // x16
        else if (cg < 102) src = hring + ((size_t)rslot * B_ + b) * H_ + (cg - 6) * 8;
        else               src = zpad;
        __builtin_amdgcn_global_load_lds(AS1C(src), AS3(Abuf + (size_t)cb * 8), 16, 0, 0);
      }
    } else if (w >= 4) {
      // hown(t) half from ring: 3072 chunks over waves 4-7 = 12 iters
      #pragma unroll
      for (int i = 0; i < 12; ++i) {
        int cb = (w - 4) * 768 + i * 64;
        int idx = cb + lane;
        int row = idx / 96;
        int c = idx - row * 96;
        int cg = c ^ (row & 7);
        int b = btile * 32 + row;
        const f16* src = hring + ((size_t)rslot * B_ + b) * H_ + cg * 8;
        __builtin_amdgcn_global_load_lds(AS1C(src), AS3(Abuf + (size_t)(32 * 768 + cb * 8)), 16, 0, 0);
      }
    }
    asm volatile("s_waitcnt vmcnt(0)" ::: "memory");
    __syncthreads();

    // ---- MFMA: wave tile 32 rows x 48 cols over its k-quarter
    f32x4 acc[2][3] = {};
    const char* Ab = (const char*)(Abuf + (L == 0 ? 0 : (kw >> 1) * 32 * 768));
    const int cbase = (L == 0) ? kw * 32 : (kw & 1) * 48;
    #pragma unroll
    for (int kt = 0; kt < NKT; ++kt) {
      int c = cbase + kt * 4 + (lane >> 4);
      int row0 = (lane & 15);
      half8 a0 = *(const half8*)(Ab + (size_t)row0 * (CH * 16) + (size_t)(c ^ (row0 & 7)) * 16);
      int row1 = 16 + (lane & 15);
      half8 a1 = *(const half8*)(Ab + (size_t)row1 * (CH * 16) + (size_t)(c ^ (row1 & 7)) * 16);
      #pragma unroll
      for (int ct = 0; ct < 3; ++ct) {
        acc[0][ct] = __builtin_amdgcn_mfma_f32_16x16x32_f16(a0, breg[ct * NKT + kt], acc[0][ct], 0, 0, 0);
        acc[1][ct] = __builtin_amdgcn_mfma_f32_16x16x32_f16(a1, breg[ct * NKT + kt], acc[1][ct], 0, 0, 0);
      }
    }

    // ---- partial Z -> LDS, stride-96 layout: addr = kw*3072 + row*96 + col
    {
      float* zr = zred + kw * 3072;
      #pragma unroll
      for (int rt = 0; rt < 2; ++rt) {
        #pragma unroll
        for (int ct = 0; ct < 3; ++ct) {
          int row = rt * 16 + (lane >> 4) * 4;
          int col = cw * 48 + ct * 16 + (lane & 15);
          #pragma unroll
          for (int r4 = 0; r4 < 4; ++r4)
            zr[(size_t)(row + r4) * 96 + col] = acc[rt][ct][r4];
        }
      }
    }
    __syncthreads();

    // ---- waves 6,7: prefetch hin(t+1)'s slot (t+2) while others do gates
    if (tid >= 384) {
      if (L > 0 && t + 1 < T_) stage_hin(t + 2);
    } else {
      // gate item: reads are lane-linear (id*8 dwords)
      const float* z = zred + (size_t)id * 8;
      f32x4 za = *(const f32x4*)(z)        + *(const f32x4*)(z + 3072)
               + *(const f32x4*)(z + 6144) + *(const f32x4*)(z + 9216);
      f32x4 zb = *(const f32x4*)(z + 4)        + *(const f32x4*)(z + 3076)
               + *(const f32x4*)(z + 6148)     + *(const f32x4*)(z + 9220);
      za += *(const f32x4*)(bqs + gjp * 8);
      zb += *(const f32x4*)(bqs + gjp * 8 + 4);
      float i0 = sigmoid_f(za[0]), f0 = sigmoid_f(za[1]), g0 = tanh_f(za[2]), o0 = sigmoid_f(za[3]);
      float i1 = sigmoid_f(zb[0]), f1 = sigmoid_f(zb[1]), g1 = tanh_f(zb[2]), o1 = sigmoid_f(zb[3]);
      float cn0 = f0 * c0 + i0 * g0;
      float cn1 = f1 * c1 + i1 * g1;
      c0 = cn0; c1 = cn1;
      float h0 = o0 * tanh_f(cn0);
      float h1 = o1 * tanh_f(cn1);
      f16 hh0 = (f16)h0, hh1 = (f16)h1;
      unsigned u = ((unsigned)__builtin_bit_cast(uint16_t, hh1) << 16)
                 |  (unsigned)__builtin_bit_cast(uint16_t, hh0);
      // ring store: next step's recurrence read, stays dirty in THIS XCD's L2
      unsigned* rp = (unsigned*)(hring + ((size_t)((t + 1) & (RS_ - 1)) * B_ + gb) * H_ + ghc0);
      __hip_atomic_store(rp, u, __ATOMIC_RELAXED, __HIP_MEMORY_SCOPE_WORKGROUP);
      if (L < 2) {
        // time-indexed array store: next layer's (prefetched) hin
        unsigned* hp = (unsigned*)(hown + ((size_t)(t + 1) * B_ + gb) * H_ + ghc0);
        __hip_atomic_store(hp, u, __ATOMIC_RELAXED, __HIP_MEMORY_SCOPE_WORKGROUP);
      } else {
        oa0 += h0; oa1 += h1;
        if (t == T_ - 1) {
          out[(size_t)gb * H_ + ghc0]     = oa0 * (1.f / T_);
          out[(size_t)gb * H_ + ghc0 + 1] = oa1 * (1.f / T_);
        }
      }
    }

    // ---- drain h-stores to L2 (gate waves only; prefetch waves keep loads in flight)
    if (tid < 384) { asm volatile("s_waitcnt vmcnt(0)" ::: "memory"); }
    __syncthreads();
    ++iter;
    // ---- two-tier distributed barrier:
    //  arrive: rotated fast flag (workgroup scope -> local L2; fresh address
    //  each step => consumer's first normal load is an L1-miss -> L2 hit)
    //  + agent flag (L3) for the fallback path. Monotone iters => a stale L1
    //  line can only cause a false NEGATIVE (slow path), never a false pass.
    if (w == 5) {
      if (lane == 0) {
        __hip_atomic_store(flgW + ((size_t)(iter & (FR_ - 1)) * 32 + ntile) * 32, iter,
                           __ATOMIC_RELAXED, __HIP_MEMORY_SCOPE_WORKGROUP);
        __hip_atomic_store(flg + (size_t)ntile * 32, iter,
                           __ATOMIC_RELAXED, __HIP_MEMORY_SCOPE_AGENT);
      }
      volatile const unsigned* fw =
          flgW + ((size_t)(iter & (FR_ - 1)) * 32 + (lane & 31)) * 32;
      unsigned v = *fw;
      if (__ballot(v >= iter) != ~0ull) {
        unsigned* fp = flg + (size_t)(lane & 31) * 32;
        for (;;) {
          v = __hip_atomic_load(fp, __ATOMIC_RELAXED, __HIP_MEMORY_SCOPE_AGENT);
          if (__ballot(v >= iter) == ~0ull) break;
          __builtin_amdgcn_s_sleep(1);
        }
      }
    }
    __syncthreads();
  }
}

__global__ __launch_bounds__(512, 2) void lstm_main(Params p) {
  __shared__ __align__(16) f16 Abuf[2 * 32 * 768];        // 96 KB
  __shared__ __align__(16) float zred[4 * 32 * 96];       // 48 KB (4 k-partials)
  __shared__ __align__(16) float bqs[96];
  __shared__ unsigned claim_s[2];

  const int tid = threadIdx.x;
  const int lane = tid & 63;
  const int w = tid >> 6;                  // 0..7
  const int kw = w >> 1, cw = w & 1;       // k-quarter 0..3, col-half 0..1

  // ---- dynamic XCD-local grouping (r8/r9-proven): group = PHYSICAL XCD,
  // ntile = claim order. 148 KB LDS => 1 WG/CU => exactly 32 WGs per XCD.
  if (tid == 0) {
    unsigned xcc;
    asm volatile("s_getreg_b32 %0, hwreg(HW_REG_XCC_ID)" : "=s"(xcc));
    xcc &= 7u;
    unsigned slot = __hip_atomic_fetch_add(p.claim + xcc, 1u,
                                           __ATOMIC_RELAXED, __HIP_MEMORY_SCOPE_AGENT);
    claim_s[0] = xcc;
    claim_s[1] = slot & 31u;
  }
  __syncthreads();
  const int btile = (int)claim_s[0];       // batch tile == XCD id
  const int ntile = (int)claim_s[1];       // 0..31 (96 gate cols)
  unsigned* flg  = p.cnt  + (size_t)btile * 1024;          // 32 agent flags x 128B
  unsigned* flgW = p.flgW + (size_t)btile * (FR_ * 32 * 32); // rotated fast flags
  const int n0 = ntile * 96;
  unsigned iter = 0;

  f16* ring0 = p.ring;
  f16* ring1 = p.ring + (size_t)RS_ * BH_;
  f16* ring2 = p.ring + (size_t)2 * RS_ * BH_;

  run_layer<0>(p.wt0, p.x16, p.hs0, ring0, p.bq + 0 * NG_ + n0, p.zpad, p.out, flg, flgW, iter,
               Abuf, zred, bqs, tid, lane, w, kw, cw, btile, ntile, n0);
  run_layer<1>(p.wt1, p.hs0, p.hs1, ring1, p.bq + 1 * NG_ + n0, p.zpad, p.out, flg, flgW, iter,
               Abuf, zred, bqs, tid, lane, w, kw, cw, btile, ntile, n0);
  run_layer<2>(p.wt2, p.hs1, (f16*)nullptr, ring2, p.bq + 2 * NG_ + n0, p.zpad, p.out, flg, flgW, iter,
               Abuf, zred, bqs, tid, lane, w, kw, cw, btile, ntile, n0);
}

extern "C" void kernel_launch(void* const* d_in, const int* in_sizes, int n_in,
                              void* d_out, int out_size, void* d_ws, size_t ws_size,
                              hipStream_t stream) {
  const float* x   = (const float*)d_in[0];
  const float* Wi0 = (const float*)d_in[1];
  const float* Wh0 = (const float*)d_in[2];
  const float* b0  = (const float*)d_in[3];
  const float* Wi1 = (const float*)d_in[4];
  const float* Wh1 = (const float*)d_in[5];
  const float* b1  = (const float*)d_in[6];
  const float* Wi2 = (const float*)d_in[7];
  const float* Wh2 = (const float*)d_in[8];
  const float* b2  = (const float*)d_in[9];

  char* wsb = (char*)d_ws;
  size_t off = 0;
  auto nxt = [&](size_t sz) { char* p = wsb + off; off += (sz + 255) & ~(size_t)255; return p; };
  f16*      wt0  = (f16*)nxt((size_t)NG_ * KP0_ * 2);         // 6.3 MB
  f16*      wt1  = (f16*)nxt((size_t)NG_ * KP12_ * 2);        // 9.4 MB
  f16*      wt2  = (f16*)nxt((size_t)NG_ * KP12_ * 2);        // 9.4 MB
  float*    bq   = (float*)nxt((size_t)3 * NG_ * 4);
  f16*      x16  = (f16*)nxt((size_t)T_ * B_ * XC_ * 2);      // 3.9 MB
  f16*      hs0  = (f16*)nxt((size_t)(T_ + 1) * BH_ * 2);     // 60.4 MB
  f16*      hs1  = (f16*)nxt((size_t)(T_ + 1) * BH_ * 2);     // 60.4 MB
  f16*      ring = (f16*)nxt((size_t)3 * RS_ * BH_ * 2);      // 18.9 MB
  f16*      zpad = (f16*)nxt(256);
  unsigned* cnt  = (unsigned*)nxt(8 * 1024 * 4);              // 8 groups x 32 agent flags x 128B
  unsigned* flgW = (unsigned*)nxt((size_t)8 * FR_ * 32 * 128);// 2 MB rotated fast flags
  unsigned* claim= (unsigned*)nxt(256);                       // 8 claim counters
  if (off > ws_size) return;  // insufficient workspace

  hipMemsetAsync(ring, 0, BH_ * 2, stream);                          // h0(0)=0
  hipMemsetAsync(ring + (size_t)RS_ * BH_, 0, BH_ * 2, stream);      // h1(0)=0
  hipMemsetAsync(ring + (size_t)2 * RS_ * BH_, 0, BH_ * 2, stream);  // h2(0)=0
  hipMemsetAsync(hs0, 0, BH_ * 2, stream);                           // hin slot 0 (layer1 t=0)
  hipMemsetAsync(hs1, 0, BH_ * 2, stream);                           // hin slot 0 (layer2 t=0)
  hipMemsetAsync((void*)zpad, 0, 256, stream);
  hipMemsetAsync(cnt, 0, 8 * 1024 * 4, stream);
  hipMemsetAsync(flgW, 0, (size_t)8 * FR_ * 32 * 128, stream);
  hipMemsetAsync(claim, 0, 256, stream);

  hipLaunchKernelGGL(conv_w, dim3(KP0_ / 64, 48), dim3(256), 0, stream, Wi0, Wh0, DIN_, XC_, KP0_, wt0);
  hipLaunchKernelGGL(conv_w, dim3(KP12_ / 64, 48), dim3(256), 0, stream, Wi1, Wh1, H_, H_, KP12_, wt1);
  hipLaunchKernelGGL(conv_w, dim3(KP12_ / 64, 48), dim3(256), 0, stream, Wi2, Wh2, H_, H_, KP12_, wt2);
  hipLaunchKernelGGL(conv_b, dim3((3 * NG_ + 255) / 256), dim3(256), 0, stream, b0, b1, b2, bq);
  hipLaunchKernelGGL(conv_x, dim3((T_ * B_ * XC_ + 255) / 256), dim3(256), 0, stream, x, x16);

  Params prm{wt0, wt1, wt2, bq, x16, hs0, hs1, ring, zpad, cnt, flgW, claim, (float*)d_out};
  hipLaunchKernelGGL(lstm_main, dim3(256), dim3(512), 0, stream, prm);
}